// Round 7
// baseline (124.861 us; speedup 1.0000x reference)
//
#include <hip/hip_runtime.h>

typedef _Float16 half2v __attribute__((ext_vector_type(2)));

#define NP 8192
#define KMAX 32
#define CCAP 64            // candidate cap per query (E[c]~10; P(>64) ~ 0)
#define CHUNK 1024         // points staged in LDS per chunk
#define QPB 16             // queries per block
#define LK 0.01f
#define EPSBN 1e-5f
#define NBANK 16

static constexpr int O_OUT = NP * 64;          // 524288
static constexpr int O_POS = O_OUT + NP * 3;   // 548864
static constexpr int O_BAT = O_POS + NP;       // 557056
static constexpr int O_RFL = O_BAT + NP;       // 565248
static constexpr int O_TOT = O_RFL + 4;        // 565252

// ws float offsets
#define F_ECNT  0                       // 1 int
#define F_SUMS  16                      // 16 x 64
#define F_SUMSQ (16 + 1024)             // 16 x 64
#define F_VSEL  4096                    // NP*64 (gamma-sign-selected max/min)

__device__ __forceinline__ float dot2f(half2v a, half2v b, float c) {
#if __has_builtin(__builtin_amdgcn_fdot2)
    return __builtin_amdgcn_fdot2(a, b, c, false);
#else
    return c + (float)a[0] * (float)b[0] + (float)a[1] * (float)b[1];
#endif
}

// ---------------- K1: fused radius search (LDS-staged) + per-edge MLP
// 512 blocks x 256 thr; 16 queries/block; wave w owns queries 4w..4w+3.
// waves_per_eu(2,2): 2 blocks/CU resident = whole grid in one round; 256-VGPR budget.
__global__ __launch_bounds__(256) __attribute__((amdgpu_waves_per_eu(2, 2)))
void k1_fused(const float* __restrict__ xin,
              const float* __restrict__ pos,
              const float* __restrict__ rfl,
              const float* __restrict__ sf,
              const float* __restrict__ w1,
              const float* __restrict__ b1,
              const float* __restrict__ w2,
              const float* __restrict__ b2,
              const float* __restrict__ gamma,
              const int* __restrict__ braw,
              float* __restrict__ wsf) {
    // spos (16 KB) staged candidates; reused in phase 2 as h1 tiles [4][32][64]f16
    __shared__ __align__(16) float4 spos[CHUNK];
    __shared__ int cidx[QPB][CCAP];                // 4 KB
    __shared__ float cd2[QPB][CCAP];               // 4 KB
    __shared__ __align__(16) float featw[4][32][8];// 4 KB per-wave feature tiles
    __shared__ float red[256];
    __shared__ int lcnt[QPB];
    __shared__ int bst_s[5];
    __shared__ float4 qp4[QPB];                    // (pix,piy,piz, 1/sf[b])
    __shared__ float rfl_q[QPB];
    constexpr float R2C = (float)((0.02 * 2.1) * (0.02 * 2.1));

    int t = threadIdx.x;
    int lane = t & 63;
    int w = t >> 6;
    int i0 = blockIdx.x * QPB;

    int* ecnt = (int*)wsf;
    float* sums = wsf + F_SUMS;
    float* sumsq = wsf + F_SUMSQ;
    float* vsel = wsf + F_VSEL;

    // int64 LE viewed as int32 => index NP-1 is a hi-word (0); int32 sorted => 3.
    const int is64 = (braw[NP - 1] == 0) ? 1 : 0;
    if (t == 0) { bst_s[0] = 0; bst_s[4] = NP; }
    if (t < 3) {               // lower_bound(batch >= b), b = 1..3
        int b = t + 1, lo = 0, hi = NP;
        while (lo < hi) {
            int mid = (lo + hi) >> 1;
            int v = is64 ? braw[2 * mid] : braw[mid];
            if (v < b) lo = mid + 1; else hi = mid;
        }
        bst_s[b] = lo;
    }
    if (t < QPB) lcnt[t] = 0;

    // ---- weights in registers, pinned against rematerialization; lane = channel
    float w1c[8];
#pragma unroll
    for (int f = 0; f < 8; f++) {
        w1c[f] = w1[f * 64 + lane];
        asm volatile("" : "+v"(w1c[f]));
    }
    float b1c = b1[lane];
    half2v w2c[32];
#pragma unroll
    for (int m = 0; m < 32; m++) {
        half2v v;
        v[0] = (_Float16)w2[(2 * m + 0) * 64 + lane];
        v[1] = (_Float16)w2[(2 * m + 1) * 64 + lane];
        w2c[m] = v;
        asm volatile("" : "+v"(w2c[m]));
    }
    float b2c = b2[lane];
    float gamc = gamma[lane];
    __syncthreads();

    if (t < QPB) {
        int i = i0 + t;
        int b = (i >= bst_s[1]) + (i >= bst_s[2]) + (i >= bst_s[3]);
        qp4[t] = make_float4(pos[3 * i], pos[3 * i + 1], pos[3 * i + 2], 1.0f / sf[b]);
        rfl_q[t] = rfl[i];
    }
    __syncthreads();

    // ---- wave's 4 queries in registers
    int qbase = w * 4;
    float qx[4], qy[4], qz[4], qs[4];
    int ql[4], qh[4];
#pragma unroll
    for (int q = 0; q < 4; q++) {
        int i = i0 + qbase + q;
        float4 p = qp4[qbase + q];
        qx[q] = p.x; qy[q] = p.y; qz[q] = p.z;
        qs[q] = p.x * p.x + p.y * p.y + p.z * p.z;
        int b = (i >= bst_s[1]) + (i >= bst_s[2]) + (i >= bst_s[3]);
        ql[q] = bst_s[b]; qh[q] = bst_s[b + 1];
    }
    // block-wide scan range (batch sorted: union = [seg(i0).lo, seg(i0+15).hi))
    int lob, hib;
    {
        int bA = (i0 >= bst_s[1]) + (i0 >= bst_s[2]) + (i0 >= bst_s[3]);
        int iZ = i0 + QPB - 1;
        int bZ = (iZ >= bst_s[1]) + (iZ >= bst_s[2]) + (iZ >= bst_s[3]);
        lob = bst_s[bA]; hib = bst_s[bZ + 1];
    }

    // ---- phase 1: chunked LDS-staged scan; each wave tests its 4 queries
    for (int base = lob; base < hib; base += CHUNK) {
        int csz = min(CHUNK, hib - base);
        __syncthreads();
        for (int k = t; k < csz; k += 256) {
            int j = base + k;
            float xj = pos[3 * j], yj = pos[3 * j + 1], zj = pos[3 * j + 2];
            spos[k] = make_float4(xj, yj, zj, xj * xj + yj * yj + zj * zj);
        }
        __syncthreads();
        for (int k = lane; k < csz; k += 64) {
            float4 pj = spos[k];          // one ds_read_b128 per candidate
            int j = base + k;
#pragma unroll
            for (int q = 0; q < 4; q++) {
                if (j >= ql[q] && j < qh[q]) {
                    float d2 = qs[q] + pj.w - 2.0f * (qx[q] * pj.x + qy[q] * pj.y + qz[q] * pj.z);
                    if (d2 < R2C) {
                        int p = atomicAdd(&lcnt[qbase + q], 1);
                        if (p < CCAP) { cidx[qbase + q][p] = j; cd2[qbase + q][p] = d2; }
                    }
                }
            }
        }
    }
    __syncthreads();
    if (t < QPB) {             // rare overflow: exact nearest-KMAX selection
        int c = lcnt[t]; c = c > CCAP ? CCAP : c;
        if (c > KMAX) {
            for (int s = 0; s < KMAX; s++) {
                int bi = s; float bd = cd2[t][s];
                for (int r = s + 1; r < c; r++)
                    if (cd2[t][r] < bd) { bd = cd2[t][r]; bi = r; }
                float tf = cd2[t][s]; cd2[t][s] = cd2[t][bi]; cd2[t][bi] = tf;
                int ti = cidx[t][s]; cidx[t][s] = cidx[t][bi]; cidx[t][bi] = ti;
            }
            c = KMAX;
        }
        lcnt[t] = c;
    }
    __syncthreads();

    // ---- phase 2: wave processes its own 4 queries; intra-wave sync only
    _Float16 (*h1w)[64] = ((_Float16 (*)[64])spos) + w * 32;  // 32 edges x 64 f16
    float ssum = 0.f, ssq = 0.f;
#pragma unroll 1
    for (int qq = 0; qq < 4; qq++) {
        int q = qbase + qq;
        int i = i0 + q;
        int c = lcnt[q];
        float4 qv = qp4[q];
        float riq = rfl_q[q];
        float vmax = -3.4e38f, vmin = 3.4e38f;
        for (int tb = 0; tb < c; tb += 32) {
            int n = min(32, c - tb);
            if (lane < n) {            // cooperative feature build, lane = edge
                int j = cidx[q][tb + lane];
                float rs = qv.w;
                float4 x4 = ((const float4*)xin)[j];
                float4 fb;
                fb.x = (pos[3 * j + 0] - qv.x) * rs;
                fb.y = (pos[3 * j + 1] - qv.y) * rs;
                fb.z = (pos[3 * j + 2] - qv.z) * rs;
                fb.w = rfl[j] - riq;
                ((float4*)featw[w][lane])[0] = x4;
                ((float4*)featw[w][lane])[1] = fb;
            }
            asm volatile("s_waitcnt lgkmcnt(0)" ::: "memory");
            // 2a: h1 for the tile (independent edges -> pipelined)
            for (int e = 0; e < n; e++) {
                float4 fa = ((const float4*)featw[w][e])[0];
                float4 fb = ((const float4*)featw[w][e])[1];
                float a = b1c + fa.x * w1c[0] + fa.y * w1c[1] + fa.z * w1c[2] + fa.w * w1c[3]
                              + fb.x * w1c[4] + fb.y * w1c[5] + fb.z * w1c[6] + fb.w * w1c[7];
                float h1 = a > 0.f ? a : LK * a;
                h1w[e][lane] = (_Float16)h1;
            }
            asm volatile("s_waitcnt lgkmcnt(0)" ::: "memory");
            // 2b: layer 2 (independent edges -> pipelined broadcast reads)
            for (int e = 0; e < n; e++) {
                const float4* hp = (const float4*)h1w[e];
                float acc = b2c;
#pragma unroll
                for (int k = 0; k < 8; k++) {
                    float4 rv = hp[k];             // broadcast b128 = 8 halves
                    half2v* h2p = (half2v*)&rv;
                    acc = dot2f(h2p[0], w2c[4 * k + 0], acc);
                    acc = dot2f(h2p[1], w2c[4 * k + 1], acc);
                    acc = dot2f(h2p[2], w2c[4 * k + 2], acc);
                    acc = dot2f(h2p[3], w2c[4 * k + 3], acc);
                }
                float h2 = acc > 0.f ? acc : LK * acc;
                vmax = fmaxf(vmax, h2);
                vmin = fminf(vmin, h2);
                ssum += h2; ssq += h2 * h2;
            }
        }
        // sign(scl) = sign(gamma): select now, one store (c>=1: self-edge)
        vsel[i * 64 + lane] = (gamc >= 0.f) ? vmax : vmin;
    }

    // ---- BN stats: block-reduce then 16-way banked atomics
    red[t] = ssum;
    __syncthreads();
    if (t < 64) atomicAdd(&sums[((blockIdx.x & (NBANK - 1)) << 6) + t],
                          red[t] + red[t + 64] + red[t + 128] + red[t + 192]);
    __syncthreads();
    red[t] = ssq;
    __syncthreads();
    if (t < 64) atomicAdd(&sumsq[((blockIdx.x & (NBANK - 1)) << 6) + t],
                          red[t] + red[t + 64] + red[t + 128] + red[t + 192]);
    if (t == 0) {
        int tot = 0;
#pragma unroll
        for (int q = 0; q < QPB; q++) tot += lcnt[q];
        atomicAdd(ecnt, tot);
    }
}

// ---------------- K2: BN affine + tuple passthrough, float4-vectorized
__global__ __launch_bounds__(256) void k2_fin(const float* __restrict__ wsf,
                                              const float* __restrict__ gamma,
                                              const float* __restrict__ beta,
                                              const float* __restrict__ pos,
                                              const int* __restrict__ braw,
                                              const float* __restrict__ rfl,
                                              const float* __restrict__ sf,
                                              float* __restrict__ out) {
    __shared__ float scl_s[64], shf_s[64];
    int tid = threadIdx.x;
    if (tid < 64) {
        float s = 0.f, s2 = 0.f;
#pragma unroll
        for (int b = 0; b < NBANK; b++) {
            s += wsf[F_SUMS + b * 64 + tid];
            s2 += wsf[F_SUMSQ + b * 64 + tid];
        }
        float cntf = (float)((const int*)wsf)[F_ECNT];
        float mean = s / cntf;
        float var = s2 / cntf - mean * mean;
        var = var > 0.f ? var : 0.f;
        float inv = 1.0f / sqrtf(var + EPSBN);
        float scl = gamma[tid] * inv;
        scl_s[tid] = scl;
        shf_s[tid] = beta[tid] - mean * scl;
    }
    __syncthreads();
    int o4 = blockIdx.x * 256 + tid;       // float4 index
    int o = o4 * 4;
    if (o >= O_TOT) return;
    float4 r;
    if (o < O_OUT) {
        float4 v = ((const float4*)(wsf + F_VSEL))[o4];
        int c = o & 63;
        r.x = scl_s[c + 0] * v.x + shf_s[c + 0];
        r.y = scl_s[c + 1] * v.y + shf_s[c + 1];
        r.z = scl_s[c + 2] * v.z + shf_s[c + 2];
        r.w = scl_s[c + 3] * v.w + shf_s[c + 3];
    } else if (o < O_POS) {
        r = ((const float4*)pos)[(o - O_OUT) >> 2];
    } else if (o < O_BAT) {
        int i = o - O_POS;
        int is64 = (braw[NP - 1] == 0) ? 1 : 0;
        r.x = (float)(is64 ? braw[2 * (i + 0)] : braw[i + 0]);
        r.y = (float)(is64 ? braw[2 * (i + 1)] : braw[i + 1]);
        r.z = (float)(is64 ? braw[2 * (i + 2)] : braw[i + 2]);
        r.w = (float)(is64 ? braw[2 * (i + 3)] : braw[i + 3]);
    } else if (o < O_RFL) {
        r = ((const float4*)rfl)[(o - O_BAT) >> 2];
    } else {
        r = ((const float4*)sf)[0];
    }
    ((float4*)out)[o4] = r;
}

extern "C" void kernel_launch(void* const* d_in, const int* in_sizes, int n_in,
                              void* d_out, int out_size, void* d_ws, size_t ws_size,
                              hipStream_t stream) {
    const float* xin  = (const float*)d_in[0];
    const float* pos  = (const float*)d_in[1];
    const float* rfl  = (const float*)d_in[2];
    const float* sf   = (const float*)d_in[3];
    const float* w1   = (const float*)d_in[4];
    const float* b1   = (const float*)d_in[5];
    const float* w2   = (const float*)d_in[6];
    const float* b2   = (const float*)d_in[7];
    const float* gam  = (const float*)d_in[8];
    const float* bet  = (const float*)d_in[9];
    const int*   brw  = (const int*)d_in[10];
    float* out = (float*)d_out;
    float* wsf = (float*)d_ws;

    hipMemsetAsync(d_ws, 0, (F_SUMSQ + 1024) * 4, stream);   // ecnt + sums + sumsq

    k1_fused<<<NP / QPB, 256, 0, stream>>>(xin, pos, rfl, sf, w1, b1, w2, b2,
                                           gam, brw, wsf);
    int n4 = (O_TOT + 3) / 4;
    k2_fin<<<(n4 + 255) / 256, 256, 0, stream>>>(wsf, gam, bet, pos, brw, rfl, sf, out);
}

// Round 8
// 117.007 us; speedup vs baseline: 1.0671x; 1.0671x over previous
//
#include <hip/hip_runtime.h>

typedef _Float16 half2v __attribute__((ext_vector_type(2)));

#define NP 8192
#define KMAX 32
#define CCAP 64            // candidate cap per query (E[c]~10; P(>64) ~ 0)
#define QPB 8              // queries per block
#define LK 0.01f
#define EPSBN 1e-5f
#define NBANK 16

static constexpr int O_OUT = NP * 64;          // 524288
static constexpr int O_POS = O_OUT + NP * 3;   // 548864
static constexpr int O_BAT = O_POS + NP;       // 557056
static constexpr int O_RFL = O_BAT + NP;       // 565248
static constexpr int O_TOT = O_RFL + 4;        // 565252

// ws float offsets
#define F_ECNT  0                       // 1 int
#define F_SUMS  16                      // 16 x 64
#define F_SUMSQ (16 + 1024)             // 16 x 64
#define F_VSEL  4096                    // NP*64 (gamma-sign-selected max/min)

__device__ __forceinline__ float dot2f(half2v a, half2v b, float c) {
#if __has_builtin(__builtin_amdgcn_fdot2)
    return __builtin_amdgcn_fdot2(a, b, c, false);
#else
    return c + (float)a[0] * (float)b[0] + (float)a[1] * (float)b[1];
#endif
}

// ---------------- K1: fused radius search (register-resident, zero phase-1 LDS
// traffic) + per-edge MLP. 1024 blocks x 256 thr; 8 queries/block; scan splits
// candidates across all 256 threads, each tests its candidate vs all 8 queries
// in registers. Phase 2: wave w owns queries 2w,2w+1; LDS ops are broadcasts.
__global__ __launch_bounds__(256) __attribute__((amdgpu_waves_per_eu(4, 4)))
void k1_fused(const float* __restrict__ xin,
              const float* __restrict__ pos,
              const float* __restrict__ rfl,
              const float* __restrict__ sf,
              const float* __restrict__ w1,
              const float* __restrict__ b1,
              const float* __restrict__ w2,
              const float* __restrict__ b2,
              const float* __restrict__ gamma,
              const int* __restrict__ braw,
              float* __restrict__ wsf) {
    __shared__ int cidx[QPB][CCAP];                 // 2 KB
    __shared__ float cd2[QPB][CCAP];                // 2 KB
    __shared__ __align__(16) _Float16 h1w[4][32][64];  // 16 KB h1 tiles
    __shared__ __align__(16) float featw[4][32][8];    // 4 KB feature tiles
    __shared__ float red[256];
    __shared__ int lcnt[QPB];
    __shared__ int bst_s[5];
    __shared__ float4 qp4[QPB];                     // (pix,piy,piz, 1/sf[b])
    __shared__ float rfl_q[QPB];
    constexpr float R2C = (float)((0.02 * 2.1) * (0.02 * 2.1));

    int t = threadIdx.x;
    int lane = t & 63;
    int w = t >> 6;
    int i0 = blockIdx.x * QPB;

    int* ecnt = (int*)wsf;
    float* sums = wsf + F_SUMS;
    float* sumsq = wsf + F_SUMSQ;
    float* vsel = wsf + F_VSEL;

    // int64 LE viewed as int32 => index NP-1 is a hi-word (0); int32 sorted => 3.
    const int is64 = (braw[NP - 1] == 0) ? 1 : 0;
    if (t == 0) { bst_s[0] = 0; bst_s[4] = NP; }
    if (t < 3) {               // lower_bound(batch >= b), b = 1..3
        int b = t + 1, lo = 0, hi = NP;
        while (lo < hi) {
            int mid = (lo + hi) >> 1;
            int v = is64 ? braw[2 * mid] : braw[mid];
            if (v < b) lo = mid + 1; else hi = mid;
        }
        bst_s[b] = lo;
    }
    if (t < QPB) lcnt[t] = 0;

    // ---- weights in registers, pinned; lane = output channel
    float w1c[8];
#pragma unroll
    for (int f = 0; f < 8; f++) {
        w1c[f] = w1[f * 64 + lane];
        asm volatile("" : "+v"(w1c[f]));
    }
    float b1c = b1[lane];
    half2v w2c[32];
#pragma unroll
    for (int m = 0; m < 32; m++) {
        half2v v;
        v[0] = (_Float16)w2[(2 * m + 0) * 64 + lane];
        v[1] = (_Float16)w2[(2 * m + 1) * 64 + lane];
        w2c[m] = v;
        asm volatile("" : "+v"(w2c[m]));
    }
    float b2c = b2[lane];
    float gamc = gamma[lane];
    __syncthreads();

    if (t < QPB) {
        int i = i0 + t;
        int b = (i >= bst_s[1]) + (i >= bst_s[2]) + (i >= bst_s[3]);
        qp4[t] = make_float4(pos[3 * i], pos[3 * i + 1], pos[3 * i + 2], 1.0f / sf[b]);
        rfl_q[t] = rfl[i];
    }
    __syncthreads();

    // ---- all 8 queries in registers (shared by every thread of the block)
    float qx[QPB], qy[QPB], qz[QPB], qs[QPB];
    int ql[QPB], qh[QPB];
#pragma unroll
    for (int q = 0; q < QPB; q++) {
        float4 p = qp4[q];
        qx[q] = p.x; qy[q] = p.y; qz[q] = p.z;
        qs[q] = p.x * p.x + p.y * p.y + p.z * p.z;
        int i = i0 + q;
        int b = (i >= bst_s[1]) + (i >= bst_s[2]) + (i >= bst_s[3]);
        ql[q] = bst_s[b]; qh[q] = bst_s[b + 1];
    }
    const int lob = ql[0], hib = qh[QPB - 1];   // sorted batches

    // ---- phase 1: candidate-split scan, registers only, software-pipelined
    {
        int k = lob + t;
        float cx = 0.f, cy = 0.f, cz = 0.f;
        if (k < hib) { cx = pos[3 * k]; cy = pos[3 * k + 1]; cz = pos[3 * k + 2]; }
        while (k < hib) {
            int kn = k + 256;
            float nx = cx, ny = cy, nz = cz;
            if (kn < hib) { nx = pos[3 * kn]; ny = pos[3 * kn + 1]; nz = pos[3 * kn + 2]; }
            float sj = cx * cx + cy * cy + cz * cz;
#pragma unroll
            for (int q = 0; q < QPB; q++) {
                if (k >= ql[q] && k < qh[q]) {
                    float d2 = fmaf(-2.0f, qx[q] * cx + qy[q] * cy + qz[q] * cz, qs[q] + sj);
                    if (d2 < R2C) {
                        int p = atomicAdd(&lcnt[q], 1);
                        if (p < CCAP) { cidx[q][p] = k; cd2[q][p] = d2; }
                    }
                }
            }
            cx = nx; cy = ny; cz = nz; k = kn;
        }
    }
    __syncthreads();
    if (t < QPB) {             // rare overflow: exact nearest-KMAX selection
        int c = lcnt[t]; c = c > CCAP ? CCAP : c;
        if (c > KMAX) {
            for (int s = 0; s < KMAX; s++) {
                int bi = s; float bd = cd2[t][s];
                for (int r = s + 1; r < c; r++)
                    if (cd2[t][r] < bd) { bd = cd2[t][r]; bi = r; }
                float tf = cd2[t][s]; cd2[t][s] = cd2[t][bi]; cd2[t][bi] = tf;
                int ti = cidx[t][s]; cidx[t][s] = cidx[t][bi]; cidx[t][bi] = ti;
            }
            c = KMAX;
        }
        lcnt[t] = c;
    }
    __syncthreads();

    // ---- phase 2: wave w owns queries 2w, 2w+1; intra-wave sync only
    float ssum = 0.f, ssq = 0.f;
#pragma unroll 1
    for (int qq = 0; qq < 2; qq++) {
        int q = 2 * w + qq;
        int i = i0 + q;
        int c = lcnt[q];
        float4 qv = qp4[q];
        float riq = rfl_q[q];
        float vmax = -3.4e38f, vmin = 3.4e38f;
        for (int tb = 0; tb < c; tb += 32) {
            int n = min(32, c - tb);
            if (lane < n) {            // cooperative feature build, lane = edge
                int j = cidx[q][tb + lane];
                float rs = qv.w;
                float4 x4 = ((const float4*)xin)[j];
                float4 fb;
                fb.x = (pos[3 * j + 0] - qv.x) * rs;
                fb.y = (pos[3 * j + 1] - qv.y) * rs;
                fb.z = (pos[3 * j + 2] - qv.z) * rs;
                fb.w = rfl[j] - riq;
                ((float4*)featw[w][lane])[0] = x4;
                ((float4*)featw[w][lane])[1] = fb;
            }
            asm volatile("s_waitcnt lgkmcnt(0)" ::: "memory");
            // 2a: h1 tile (independent edges; broadcast reads)
            for (int e = 0; e < n; e++) {
                float4 fa = ((const float4*)featw[w][e])[0];
                float4 fb = ((const float4*)featw[w][e])[1];
                float a = b1c + fa.x * w1c[0] + fa.y * w1c[1] + fa.z * w1c[2] + fa.w * w1c[3]
                              + fb.x * w1c[4] + fb.y * w1c[5] + fb.z * w1c[6] + fb.w * w1c[7];
                float h1 = a > 0.f ? a : LK * a;
                h1w[w][e][lane] = (_Float16)h1;
            }
            asm volatile("s_waitcnt lgkmcnt(0)" ::: "memory");
            // 2b: layer 2; 2 accumulators break the dot2 dependency chain
            for (int e = 0; e < n; e++) {
                const float4* hp = (const float4*)h1w[w][e];
                float acc0 = b2c, acc1 = 0.f;
#pragma unroll
                for (int k = 0; k < 8; k++) {
                    float4 rv = hp[k];             // broadcast b128 = 8 halves
                    half2v* h2p = (half2v*)&rv;
                    acc0 = dot2f(h2p[0], w2c[4 * k + 0], acc0);
                    acc1 = dot2f(h2p[1], w2c[4 * k + 1], acc1);
                    acc0 = dot2f(h2p[2], w2c[4 * k + 2], acc0);
                    acc1 = dot2f(h2p[3], w2c[4 * k + 3], acc1);
                }
                float accf = acc0 + acc1;
                float h2 = accf > 0.f ? accf : LK * accf;
                vmax = fmaxf(vmax, h2);
                vmin = fminf(vmin, h2);
                ssum += h2; ssq += h2 * h2;
            }
        }
        // sign(scl) = sign(gamma): select now, one store (c>=1: self-edge)
        vsel[i * 64 + lane] = (gamc >= 0.f) ? vmax : vmin;
    }

    // ---- BN stats: block-reduce then 16-way banked atomics
    red[t] = ssum;
    __syncthreads();
    if (t < 64) atomicAdd(&sums[((blockIdx.x & (NBANK - 1)) << 6) + t],
                          red[t] + red[t + 64] + red[t + 128] + red[t + 192]);
    __syncthreads();
    red[t] = ssq;
    __syncthreads();
    if (t < 64) atomicAdd(&sumsq[((blockIdx.x & (NBANK - 1)) << 6) + t],
                          red[t] + red[t + 64] + red[t + 128] + red[t + 192]);
    if (t == 0) {
        int tot = 0;
#pragma unroll
        for (int q = 0; q < QPB; q++) tot += lcnt[q];
        atomicAdd(ecnt, tot);
    }
}

// ---------------- K2: BN affine + tuple passthrough, float4-vectorized
__global__ __launch_bounds__(256) void k2_fin(const float* __restrict__ wsf,
                                              const float* __restrict__ gamma,
                                              const float* __restrict__ beta,
                                              const float* __restrict__ pos,
                                              const int* __restrict__ braw,
                                              const float* __restrict__ rfl,
                                              const float* __restrict__ sf,
                                              float* __restrict__ out) {
    __shared__ float scl_s[64], shf_s[64];
    int tid = threadIdx.x;
    if (tid < 64) {
        float s = 0.f, s2 = 0.f;
#pragma unroll
        for (int b = 0; b < NBANK; b++) {
            s += wsf[F_SUMS + b * 64 + tid];
            s2 += wsf[F_SUMSQ + b * 64 + tid];
        }
        float cntf = (float)((const int*)wsf)[F_ECNT];
        float mean = s / cntf;
        float var = s2 / cntf - mean * mean;
        var = var > 0.f ? var : 0.f;
        float inv = 1.0f / sqrtf(var + EPSBN);
        float scl = gamma[tid] * inv;
        scl_s[tid] = scl;
        shf_s[tid] = beta[tid] - mean * scl;
    }
    __syncthreads();
    int o4 = blockIdx.x * 256 + tid;       // float4 index
    int o = o4 * 4;
    if (o >= O_TOT) return;
    float4 r;
    if (o < O_OUT) {
        float4 v = ((const float4*)(wsf + F_VSEL))[o4];
        int c = o & 63;
        r.x = scl_s[c + 0] * v.x + shf_s[c + 0];
        r.y = scl_s[c + 1] * v.y + shf_s[c + 1];
        r.z = scl_s[c + 2] * v.z + shf_s[c + 2];
        r.w = scl_s[c + 3] * v.w + shf_s[c + 3];
    } else if (o < O_POS) {
        r = ((const float4*)pos)[(o - O_OUT) >> 2];
    } else if (o < O_BAT) {
        int i = o - O_POS;
        int is64 = (braw[NP - 1] == 0) ? 1 : 0;
        r.x = (float)(is64 ? braw[2 * (i + 0)] : braw[i + 0]);
        r.y = (float)(is64 ? braw[2 * (i + 1)] : braw[i + 1]);
        r.z = (float)(is64 ? braw[2 * (i + 2)] : braw[i + 2]);
        r.w = (float)(is64 ? braw[2 * (i + 3)] : braw[i + 3]);
    } else if (o < O_RFL) {
        r = ((const float4*)rfl)[(o - O_BAT) >> 2];
    } else {
        r = ((const float4*)sf)[0];
    }
    ((float4*)out)[o4] = r;
}

extern "C" void kernel_launch(void* const* d_in, const int* in_sizes, int n_in,
                              void* d_out, int out_size, void* d_ws, size_t ws_size,
                              hipStream_t stream) {
    const float* xin  = (const float*)d_in[0];
    const float* pos  = (const float*)d_in[1];
    const float* rfl  = (const float*)d_in[2];
    const float* sf   = (const float*)d_in[3];
    const float* w1   = (const float*)d_in[4];
    const float* b1   = (const float*)d_in[5];
    const float* w2   = (const float*)d_in[6];
    const float* b2   = (const float*)d_in[7];
    const float* gam  = (const float*)d_in[8];
    const float* bet  = (const float*)d_in[9];
    const int*   brw  = (const int*)d_in[10];
    float* out = (float*)d_out;
    float* wsf = (float*)d_ws;

    hipMemsetAsync(d_ws, 0, (F_SUMSQ + 1024) * 4, stream);   // ecnt + sums + sumsq

    k1_fused<<<NP / QPB, 256, 0, stream>>>(xin, pos, rfl, sf, w1, b1, w2, b2,
                                           gam, brw, wsf);
    int n4 = (O_TOT + 3) / 4;
    k2_fin<<<(n4 + 255) / 256, 256, 0, stream>>>(wsf, gam, bet, pos, brw, rfl, sf, out);
}